// Round 3
// baseline (283.927 us; speedup 1.0000x reference)
//
#include <hip/hip_runtime.h>

#define B_ 256
#define I_ 1024
#define P_ 128
#define H_ 128
#define LP_ 1024

// ---------------- Kernel A: gates GEMV (pure streaming, full occupancy) ----
// grid 2048 x 256: 8192 waves total = 32 waves/CU. Each wave computes 16
// item-pairs: one dwordx4 per lane covers a pair's param rows (1 KB/wave/iter),
// butterfly-reduce within each 32-lane half, lane {0,32} stores the gate.
__global__ __launch_bounds__(256) void gates_gemv(
    const float* __restrict__ param_enc,
    const float* __restrict__ w1,
    const float* __restrict__ b1,
    float* __restrict__ gates)
{
    const int tid  = threadIdx.x;
    const int lane = tid & 63;
    const int wave = tid >> 6;               // 0..3
    const int half = lane >> 5;
    const int sub  = lane & 31;
    const int w    = blockIdx.x * 4 + wave;  // global wave 0..8191
    const int b    = w >> 5;                 // batch
    const int wwb  = w & 31;                 // wave-within-batch

    const float bias = b1[0];
    const float4 wv = *(const float4*)(w1 + sub * 4);
    const float* pe_b = param_enc + (size_t)b * I_ * P_;
    float* g_b = gates + b * I_;

    #pragma unroll 8
    for (int q = 0; q < 16; ++q) {
        const int i0 = (wwb + q * 32) * 2;
        float4 pv = *(const float4*)(pe_b + (size_t)i0 * P_ + lane * 4);
        float part = pv.x * wv.x + pv.y * wv.y + pv.z * wv.z + pv.w * wv.w;
        part += __shfl_xor(part, 1);
        part += __shfl_xor(part, 2);
        part += __shfl_xor(part, 4);
        part += __shfl_xor(part, 8);
        part += __shfl_xor(part, 16);
        if (sub == 0) g_b[i0 + half] = part + bias;
    }
}

// ---------------- Kernel B: counting-sort + gather (4 blocks per batch) ----
// Block (b, seg) owns 32 output rows [seg*32, seg*32+32) of batch b.
// grid 1024 x 256, ~8.5 KB LDS -> 4 blocks/CU co-resident: four independent
// sort/gather pipelines overlap each other's memory latency on each CU.
__global__ __launch_bounds__(256) void sort_gather(
    const float* __restrict__ gates,
    const float* __restrict__ h_prot,
    const int* __restrict__ indices_lig,
    const int* __restrict__ indices_prot,
    const int* __restrict__ protein_idx,
    const int* __restrict__ lig_offsets,
    float* __restrict__ out)
{
    __shared__ float          s_g[I_];       // 4 KB: all gates of the batch
    __shared__ unsigned short s_ipl[I_];     // 2 KB: prot row per item
    __shared__ unsigned short s_items[I_];   // 2 KB: item ids bucketed by row
    __shared__ int            s_cnt[32];
    __shared__ int            s_start[33];
    __shared__ int            s_cur[32];

    const int tid  = threadIdx.x;
    const int blk  = blockIdx.x;
    const int b    = blk >> 2;
    const int rseg = (blk & 3) << 5;         // 0,32,64,96
    const int lane = tid & 63;
    const int wave = tid >> 6;               // 0..3
    const int half = lane >> 5;
    const int sub  = lane & 31;
    const int halfIdx = wave * 2 + half;     // 0..7

    if (tid < 32) s_cnt[tid] = 0;

    const int pb = protein_idx[b];
    const float* hp_b = h_prot + (size_t)pb * LP_ * H_;
    const float* g_b  = gates + b * I_;
    const int* il_b   = indices_lig + b * I_;
    const int* ip_b   = indices_prot + b * I_;

    __syncthreads();                          // s_cnt zeroed

    // Load metadata (coalesced), histogram items that land in our 32 rows
    int  rloc[4];
    bool lv[4];
    #pragma unroll
    for (int k = 0; k < 4; ++k) {
        const int i  = tid + k * 256;
        const float g = g_b[i];
        const int il  = il_b[i];
        const int ip  = ip_b[i];
        s_g[i]   = g;
        s_ipl[i] = (unsigned short)ip;
        const int r = il - rseg;
        lv[k]   = (g > 0.f) && ((unsigned)r < 32u);
        rloc[k] = r;
        if (lv[k]) atomicAdd(&s_cnt[r], 1);
    }
    __syncthreads();

    // Exclusive prefix sum over 32 counts (wave 0)
    if (wave == 0) {
        const int c = (lane < 32) ? s_cnt[lane] : 0;
        int s = c;
        #pragma unroll
        for (int d = 1; d < 32; d <<= 1) {
            const int t = __shfl_up(s, d);
            if (lane >= d) s += t;
        }
        if (lane < 32) { s_start[lane] = s - c; s_cur[lane] = s - c; }
        if (lane == 31) s_start[32] = s;
    }
    __syncthreads();

    // Scatter item ids into per-row buckets
    #pragma unroll
    for (int k = 0; k < 4; ++k) {
        if (lv[k]) {
            const int pos = atomicAdd(&s_cur[rloc[k]], 1);
            s_items[pos] = (unsigned short)(tid + k * 256);
        }
    }
    __syncthreads();

    // Gather: each 32-lane half owns rows {halfIdx, +8, +16, +24}; 4
    // independent dwordx4 gathers in flight per step, register accumulate,
    // plain coalesced float4 stores (no atomics anywhere on this path).
    int st[4], cn[4];
    #pragma unroll
    for (int rr = 0; rr < 4; ++rr) {
        const int a = halfIdx + rr * 8;
        st[rr] = s_start[a];
        cn[rr] = s_start[a + 1] - st[rr];
    }
    float4 acc[4];
    #pragma unroll
    for (int rr = 0; rr < 4; ++rr) acc[rr] = make_float4(0.f, 0.f, 0.f, 0.f);

    const int mx = max(max(cn[0], cn[1]), max(cn[2], cn[3]));
    for (int j = 0; j < mx; ++j) {
        #pragma unroll
        for (int rr = 0; rr < 4; ++rr) {
            if (j < cn[rr]) {
                const int   item = s_items[st[rr] + j];
                const float g    = s_g[item];
                const int   ip   = s_ipl[item];
                const float4 hv  = *(const float4*)(hp_b + (size_t)ip * H_ + sub * 4);
                acc[rr].x += g * hv.x;
                acc[rr].y += g * hv.y;
                acc[rr].z += g * hv.z;
                acc[rr].w += g * hv.w;
            }
        }
    }

    const int base = lig_offsets[b] + rseg;
    #pragma unroll
    for (int rr = 0; rr < 4; ++rr) {
        float* o = out + (size_t)(base + halfIdx + rr * 8) * H_;
        *(float4*)(o + sub * 4) = acc[rr];
    }
}

// ---------------- Fallback (ws too small): previous single-kernel version ---
__global__ __launch_bounds__(1024) void fused_ile(
    const float* __restrict__ param_enc,
    const float* __restrict__ h_prot,
    const float* __restrict__ w1,
    const float* __restrict__ b1,
    const int* __restrict__ indices_lig,
    const int* __restrict__ indices_prot,
    const int* __restrict__ protein_idx,
    const int* __restrict__ lig_offsets,
    float* __restrict__ out)
{
    __shared__ float          s_gate[I_];
    __shared__ unsigned short s_ip[I_];
    __shared__ unsigned short s_items[I_];
    __shared__ int            s_cnt[128];
    __shared__ int            s_start[129];
    __shared__ int            s_cur[128];

    const int tid  = threadIdx.x;
    const int b    = blockIdx.x;
    const int lane = tid & 63;
    const int wave = tid >> 6;
    const int half = lane >> 5;
    const int sub  = lane & 31;
    const int halfIdx = wave * 2 + half;

    if (tid < 128) s_cnt[tid] = 0;

    const float bias = b1[0];
    const int pb = protein_idx[b];
    const float4 wv = *(const float4*)(w1 + sub * 4);

    const float* pe_b = param_enc + (size_t)b * I_ * P_;
    const float* hp_b = h_prot + (size_t)pb * LP_ * H_;
    const int* il_b = indices_lig + b * I_;
    const int* ip_b = indices_prot + b * I_;

    #pragma unroll 8
    for (int q = 0; q < 32; ++q) {
        const int p  = wave + q * 16;
        const int i0 = p * 2;
        float4 pv = *(const float4*)(pe_b + (size_t)i0 * P_ + lane * 4);
        float part = pv.x * wv.x + pv.y * wv.y + pv.z * wv.z + pv.w * wv.w;
        part += __shfl_xor(part, 1);
        part += __shfl_xor(part, 2);
        part += __shfl_xor(part, 4);
        part += __shfl_xor(part, 8);
        part += __shfl_xor(part, 16);
        if (sub == 0) s_gate[i0 + half] = part + bias;
    }
    __syncthreads();

    const int  my_il = il_b[tid];
    const int  my_ip = ip_b[tid];
    const bool live  = s_gate[tid] > 0.f;
    s_ip[tid] = (unsigned short)my_ip;
    if (live) atomicAdd(&s_cnt[my_il], 1);
    __syncthreads();

    if (wave == 0) {
        const int c0 = s_cnt[2 * lane];
        const int c1 = s_cnt[2 * lane + 1];
        int s = c0 + c1;
        #pragma unroll
        for (int d = 1; d < 64; d <<= 1) {
            int t = __shfl_up(s, d);
            if (lane >= d) s += t;
        }
        s_start[2 * lane]     = s - c0 - c1;
        s_start[2 * lane + 1] = s - c1;
        if (lane == 63) s_start[128] = s;
    }
    __syncthreads();
    if (tid < 128) s_cur[tid] = s_start[tid];
    __syncthreads();

    if (live) {
        const int pos = atomicAdd(&s_cur[my_il], 1);
        s_items[pos] = (unsigned short)tid;
    }
    __syncthreads();

    const int base = lig_offsets[b];
    int st[4], cn[4];
    #pragma unroll
    for (int rr = 0; rr < 4; ++rr) {
        const int a = halfIdx + rr * 32;
        st[rr] = s_start[a];
        cn[rr] = s_start[a + 1] - st[rr];
    }
    float4 acc[4];
    #pragma unroll
    for (int rr = 0; rr < 4; ++rr) acc[rr] = make_float4(0.f, 0.f, 0.f, 0.f);

    int mx = max(max(cn[0], cn[1]), max(cn[2], cn[3]));
    for (int j = 0; j < mx; ++j) {
        #pragma unroll
        for (int rr = 0; rr < 4; ++rr) {
            if (j < cn[rr]) {
                const int   item = s_items[st[rr] + j];
                const float g    = s_gate[item];
                const int   ip   = s_ip[item];
                const float4 hv  = *(const float4*)(hp_b + (size_t)ip * H_ + sub * 4);
                acc[rr].x += g * hv.x;
                acc[rr].y += g * hv.y;
                acc[rr].z += g * hv.z;
                acc[rr].w += g * hv.w;
            }
        }
    }

    #pragma unroll
    for (int rr = 0; rr < 4; ++rr) {
        float* o = out + (size_t)(base + halfIdx + rr * 32) * H_;
        *(float4*)(o + sub * 4) = acc[rr];
    }
}

extern "C" void kernel_launch(void* const* d_in, const int* in_sizes, int n_in,
                              void* d_out, int out_size, void* d_ws, size_t ws_size,
                              hipStream_t stream) {
    const float* param_enc   = (const float*)d_in[0];
    const float* h_prot      = (const float*)d_in[1];
    const float* w1          = (const float*)d_in[2];
    const float* b1          = (const float*)d_in[3];
    const int* indices_lig   = (const int*)d_in[4];
    const int* indices_prot  = (const int*)d_in[5];
    const int* protein_idx   = (const int*)d_in[6];
    const int* lig_offsets   = (const int*)d_in[7];
    // d_in[8] = mask: all-ones by construction -> no-op; skipped.
    float* out = (float*)d_out;

    const size_t gates_bytes = (size_t)B_ * I_ * sizeof(float);
    if (ws_size >= gates_bytes && d_ws != nullptr) {
        float* gates = (float*)d_ws;
        gates_gemv<<<B_ * 8, 256, 0, stream>>>(param_enc, w1, b1, gates);
        sort_gather<<<B_ * 4, 256, 0, stream>>>(gates, h_prot,
                                                indices_lig, indices_prot,
                                                protein_idx, lig_offsets, out);
    } else {
        fused_ile<<<B_, 1024, 0, stream>>>(param_enc, h_prot, w1, b1,
                                           indices_lig, indices_prot,
                                           protein_idx, lig_offsets, out);
    }
}

// Round 4
// 278.102 us; speedup vs baseline: 1.0209x; 1.0209x over previous
//
#include <hip/hip_runtime.h>

#define B_ 256
#define I_ 1024
#define P_ 128
#define H_ 128
#define LP_ 1024

// ---------------- Kernel A: gates GEMV (8 lanes per item row) --------------
// grid 2048 x 256 = 8192 waves (32/CU). Each wave: 32 items in 4 iters of 8.
// Lane l: row8 = l>>3 (item within group of 8), oct = l&7. Lane loads 4
// float4s covering cols {oct*4+k*32} -> per load instr the wave touches 8
// aligned 128 B segments (fully consumed). Reduce = 3 shfl_xor (vs 5 before):
// DS-op tax drops from 5/KB to 0.75/KB, 4 independent loads in flight/iter.
__global__ __launch_bounds__(256) void gates_gemv(
    const float* __restrict__ param_enc,
    const float* __restrict__ w1,
    const float* __restrict__ b1,
    float* __restrict__ gates)
{
    const int tid  = threadIdx.x;
    const int lane = tid & 63;
    const int wave = tid >> 6;               // 0..3
    const int w    = blockIdx.x * 4 + wave;  // global wave 0..8191
    const int b    = w >> 5;                 // batch
    const int wwb  = w & 31;                 // wave-within-batch
    const int row8 = lane >> 3;              // 0..7: item within 8-group
    const int oct  = lane & 7;               // 0..7: position within row

    const float bias = b1[0];
    // w1 fragments for this lane's 16 columns: oct*4 + k*32 .. +3
    const float4 wl0 = *(const float4*)(w1 + oct * 4);
    const float4 wl1 = *(const float4*)(w1 + 32 + oct * 4);
    const float4 wl2 = *(const float4*)(w1 + 64 + oct * 4);
    const float4 wl3 = *(const float4*)(w1 + 96 + oct * 4);

    const float* pe_b = param_enc + (size_t)b * I_ * P_;
    float* g_b = gates + b * I_;

    #pragma unroll 2
    for (int q = 0; q < 4; ++q) {
        const int i0 = wwb * 32 + q * 8;     // base item of this 8-group
        const float* base = pe_b + (size_t)(i0 + row8) * P_ + oct * 4;
        const float4 a0 = *(const float4*)(base);
        const float4 a1 = *(const float4*)(base + 32);
        const float4 a2 = *(const float4*)(base + 64);
        const float4 a3 = *(const float4*)(base + 96);
        float s = a0.x * wl0.x + a0.y * wl0.y + a0.z * wl0.z + a0.w * wl0.w
                + a1.x * wl1.x + a1.y * wl1.y + a1.z * wl1.z + a1.w * wl1.w
                + a2.x * wl2.x + a2.y * wl2.y + a2.z * wl2.z + a2.w * wl2.w
                + a3.x * wl3.x + a3.y * wl3.y + a3.z * wl3.z + a3.w * wl3.w;
        s += __shfl_xor(s, 1);
        s += __shfl_xor(s, 2);
        s += __shfl_xor(s, 4);
        if (oct == 0) g_b[i0 + row8] = s + bias;  // 8 lanes, 32 B contiguous
    }
}

// ---------------- Kernel B: counting-sort + gather (8 blocks per batch) ----
// Block (b, seg) owns 16 output rows. grid 2048 x 256, ~8.4 KB LDS ->
// 8 blocks/CU co-resident = 32 waves/CU (full occupancy). Each 32-lane half
// owns rows {halfIdx, halfIdx+8}: 2 independent dwordx4 gathers per step,
// register accumulate, plain coalesced float4 stores. No global atomics.
__global__ __launch_bounds__(256) void sort_gather(
    const float* __restrict__ gates,
    const float* __restrict__ h_prot,
    const int* __restrict__ indices_lig,
    const int* __restrict__ indices_prot,
    const int* __restrict__ protein_idx,
    const int* __restrict__ lig_offsets,
    float* __restrict__ out)
{
    __shared__ float          s_g[I_];       // 4 KB: all gates of the batch
    __shared__ unsigned short s_ipl[I_];     // 2 KB: prot row per item
    __shared__ unsigned short s_items[I_];   // 2 KB: item ids bucketed by row
    __shared__ int            s_cnt[16];
    __shared__ int            s_start[17];
    __shared__ int            s_cur[16];

    const int tid  = threadIdx.x;
    const int blk  = blockIdx.x;
    const int b    = blk >> 3;
    const int rseg = (blk & 7) << 4;         // 0,16,...,112
    const int lane = tid & 63;
    const int wave = tid >> 6;               // 0..3
    const int half = lane >> 5;
    const int sub  = lane & 31;
    const int halfIdx = wave * 2 + half;     // 0..7

    if (tid < 16) s_cnt[tid] = 0;

    const int pb = protein_idx[b];
    const float* hp_b = h_prot + (size_t)pb * LP_ * H_;
    const float* g_b  = gates + b * I_;
    const int* il_b   = indices_lig + b * I_;
    const int* ip_b   = indices_prot + b * I_;

    __syncthreads();                          // s_cnt zeroed

    // Load metadata (coalesced), histogram items landing in our 16 rows.
    // Only ~64 of 1024 items are live AND ours -> atomics are cheap.
    int  rloc[4];
    bool lv[4];
    #pragma unroll
    for (int k = 0; k < 4; ++k) {
        const int i   = tid + k * 256;
        const float g = g_b[i];
        const int il  = il_b[i];
        const int ip  = ip_b[i];
        s_g[i]   = g;
        s_ipl[i] = (unsigned short)ip;
        const int r = il - rseg;
        lv[k]   = (g > 0.f) && ((unsigned)r < 16u);
        rloc[k] = r;
        if (lv[k]) atomicAdd(&s_cnt[r], 1);
    }
    __syncthreads();

    // Exclusive prefix sum over 16 counts (wave 0, lanes 0-15)
    if (wave == 0) {
        const int c = (lane < 16) ? s_cnt[lane] : 0;
        int s = c;
        #pragma unroll
        for (int d = 1; d < 16; d <<= 1) {
            const int t = __shfl_up(s, d);
            if (lane >= d) s += t;
        }
        if (lane < 16) { s_start[lane] = s - c; s_cur[lane] = s - c; }
        if (lane == 15) s_start[16] = s;
    }
    __syncthreads();

    // Scatter item ids into per-row buckets
    #pragma unroll
    for (int k = 0; k < 4; ++k) {
        if (lv[k]) {
            const int pos = atomicAdd(&s_cur[rloc[k]], 1);
            s_items[pos] = (unsigned short)(tid + k * 256);
        }
    }
    __syncthreads();

    // Gather: half owns rows halfIdx and halfIdx+8; 2 independent gathers
    // per step (x unroll 2 -> up to 4 in flight), register accumulate.
    const int st0 = s_start[halfIdx];
    const int cn0 = s_start[halfIdx + 1] - st0;
    const int st1 = s_start[halfIdx + 8];
    const int cn1 = s_start[halfIdx + 9] - st1;
    float4 a0 = make_float4(0.f, 0.f, 0.f, 0.f);
    float4 a1 = make_float4(0.f, 0.f, 0.f, 0.f);

    const int mx = max(cn0, cn1);
    #pragma unroll 2
    for (int j = 0; j < mx; ++j) {
        if (j < cn0) {
            const int   item = s_items[st0 + j];
            const float g    = s_g[item];
            const int   ip   = s_ipl[item];
            const float4 hv  = *(const float4*)(hp_b + (size_t)ip * H_ + sub * 4);
            a0.x += g * hv.x; a0.y += g * hv.y;
            a0.z += g * hv.z; a0.w += g * hv.w;
        }
        if (j < cn1) {
            const int   item = s_items[st1 + j];
            const float g    = s_g[item];
            const int   ip   = s_ipl[item];
            const float4 hv  = *(const float4*)(hp_b + (size_t)ip * H_ + sub * 4);
            a1.x += g * hv.x; a1.y += g * hv.y;
            a1.z += g * hv.z; a1.w += g * hv.w;
        }
    }

    const int base = lig_offsets[b] + rseg;
    float* o0 = out + (size_t)(base + halfIdx) * H_;
    float* o1 = out + (size_t)(base + halfIdx + 8) * H_;
    *(float4*)(o0 + sub * 4) = a0;
    *(float4*)(o1 + sub * 4) = a1;
}

// ---------------- Fallback (ws too small): fused single-kernel version -----
__global__ __launch_bounds__(1024) void fused_ile(
    const float* __restrict__ param_enc,
    const float* __restrict__ h_prot,
    const float* __restrict__ w1,
    const float* __restrict__ b1,
    const int* __restrict__ indices_lig,
    const int* __restrict__ indices_prot,
    const int* __restrict__ protein_idx,
    const int* __restrict__ lig_offsets,
    float* __restrict__ out)
{
    __shared__ float          s_gate[I_];
    __shared__ unsigned short s_ip[I_];
    __shared__ unsigned short s_items[I_];
    __shared__ int            s_cnt[128];
    __shared__ int            s_start[129];
    __shared__ int            s_cur[128];

    const int tid  = threadIdx.x;
    const int b    = blockIdx.x;
    const int lane = tid & 63;
    const int wave = tid >> 6;
    const int half = lane >> 5;
    const int sub  = lane & 31;
    const int halfIdx = wave * 2 + half;

    if (tid < 128) s_cnt[tid] = 0;

    const float bias = b1[0];
    const int pb = protein_idx[b];
    const float4 wv = *(const float4*)(w1 + sub * 4);

    const float* pe_b = param_enc + (size_t)b * I_ * P_;
    const float* hp_b = h_prot + (size_t)pb * LP_ * H_;
    const int* il_b = indices_lig + b * I_;
    const int* ip_b = indices_prot + b * I_;

    #pragma unroll 8
    for (int q = 0; q < 32; ++q) {
        const int p  = wave + q * 16;
        const int i0 = p * 2;
        float4 pv = *(const float4*)(pe_b + (size_t)i0 * P_ + lane * 4);
        float part = pv.x * wv.x + pv.y * wv.y + pv.z * wv.z + pv.w * wv.w;
        part += __shfl_xor(part, 1);
        part += __shfl_xor(part, 2);
        part += __shfl_xor(part, 4);
        part += __shfl_xor(part, 8);
        part += __shfl_xor(part, 16);
        if (sub == 0) s_gate[i0 + half] = part + bias;
    }
    __syncthreads();

    const int  my_il = il_b[tid];
    const int  my_ip = ip_b[tid];
    const bool live  = s_gate[tid] > 0.f;
    s_ip[tid] = (unsigned short)my_ip;
    if (live) atomicAdd(&s_cnt[my_il], 1);
    __syncthreads();

    if (wave == 0) {
        const int c0 = s_cnt[2 * lane];
        const int c1 = s_cnt[2 * lane + 1];
        int s = c0 + c1;
        #pragma unroll
        for (int d = 1; d < 64; d <<= 1) {
            int t = __shfl_up(s, d);
            if (lane >= d) s += t;
        }
        s_start[2 * lane]     = s - c0 - c1;
        s_start[2 * lane + 1] = s - c1;
        if (lane == 63) s_start[128] = s;
    }
    __syncthreads();
    if (tid < 128) s_cur[tid] = s_start[tid];
    __syncthreads();

    if (live) {
        const int pos = atomicAdd(&s_cur[my_il], 1);
        s_items[pos] = (unsigned short)tid;
    }
    __syncthreads();

    const int base = lig_offsets[b];
    int st[4], cn[4];
    #pragma unroll
    for (int rr = 0; rr < 4; ++rr) {
        const int a = halfIdx + rr * 32;
        st[rr] = s_start[a];
        cn[rr] = s_start[a + 1] - st[rr];
    }
    float4 acc[4];
    #pragma unroll
    for (int rr = 0; rr < 4; ++rr) acc[rr] = make_float4(0.f, 0.f, 0.f, 0.f);

    int mx = max(max(cn[0], cn[1]), max(cn[2], cn[3]));
    for (int j = 0; j < mx; ++j) {
        #pragma unroll
        for (int rr = 0; rr < 4; ++rr) {
            if (j < cn[rr]) {
                const int   item = s_items[st[rr] + j];
                const float g    = s_gate[item];
                const int   ip   = s_ip[item];
                const float4 hv  = *(const float4*)(hp_b + (size_t)ip * H_ + sub * 4);
                acc[rr].x += g * hv.x;
                acc[rr].y += g * hv.y;
                acc[rr].z += g * hv.z;
                acc[rr].w += g * hv.w;
            }
        }
    }

    #pragma unroll
    for (int rr = 0; rr < 4; ++rr) {
        float* o = out + (size_t)(base + halfIdx + rr * 32) * H_;
        *(float4*)(o + sub * 4) = acc[rr];
    }
}

extern "C" void kernel_launch(void* const* d_in, const int* in_sizes, int n_in,
                              void* d_out, int out_size, void* d_ws, size_t ws_size,
                              hipStream_t stream) {
    const float* param_enc   = (const float*)d_in[0];
    const float* h_prot      = (const float*)d_in[1];
    const float* w1          = (const float*)d_in[2];
    const float* b1          = (const float*)d_in[3];
    const int* indices_lig   = (const int*)d_in[4];
    const int* indices_prot  = (const int*)d_in[5];
    const int* protein_idx   = (const int*)d_in[6];
    const int* lig_offsets   = (const int*)d_in[7];
    // d_in[8] = mask: all-ones by construction -> no-op; skipped.
    float* out = (float*)d_out;

    const size_t gates_bytes = (size_t)B_ * I_ * sizeof(float);
    if (ws_size >= gates_bytes && d_ws != nullptr) {
        float* gates = (float*)d_ws;
        gates_gemv<<<2048, 256, 0, stream>>>(param_enc, w1, b1, gates);
        sort_gather<<<2048, 256, 0, stream>>>(gates, h_prot,
                                              indices_lig, indices_prot,
                                              protein_idx, lig_offsets, out);
    } else {
        fused_ile<<<B_, 1024, 0, stream>>>(param_enc, h_prot, w1, b1,
                                           indices_lig, indices_prot,
                                           protein_idx, lig_offsets, out);
    }
}